// Round 8
// baseline (241.409 us; speedup 1.0000x reference)
//
#include <hip/hip_runtime.h>
#include <hip/hip_bf16.h>

#define BB 64
#define LL 800
#define DD 100
#define NFC 50
#define MPAD 832
#define DPAD 128

typedef __attribute__((ext_vector_type(8))) short short8;
typedef __attribute__((ext_vector_type(4))) float f32x4;
#define MFMA16(a, b, c) __builtin_amdgcn_mfma_f32_16x16x32_bf16(a, b, c, 0, 0, 0)

struct ConvP {
  const float* w[8];
  const float* bias[8];
};

__device__ __forceinline__ ushort f2bf(float f) {
  unsigned u = __float_as_uint(f);
  u += 0x7fff + ((u >> 16) & 1);
  return (ushort)(u >> 16);
}
__device__ __forceinline__ float bf2f(short s) {
  return __uint_as_float(((unsigned)(ushort)s) << 16);
}
__device__ __forceinline__ unsigned cvtpk(float lo, float hi) {
  unsigned d;
  asm("v_cvt_pk_bf16_f32 %0, %1, %2" : "=v"(d) : "v"(lo), "v"(hi));
  return d;
}
__device__ __forceinline__ void swap3216(unsigned& a, unsigned& b) {
  asm("v_permlane32_swap_b32 %0, %1\n\t"
      "v_permlane16_swap_b32 %0, %1"
      : "+v"(a), "+v"(b));
}

// ---- fused gather + bf16 prep ----
// xeb[b][832][128]  : raw bf16 rows
// xeT[b][128][832]  : transposed, MASKED (d<100: x*mask; d=100: mask; d=101: 1; else 0)
__global__ __launch_bounds__(256) void k_prep(const int* __restrict__ x,
                                              const float* __restrict__ emb,
                                              const int* __restrict__ mask,
                                              short* __restrict__ xeb,
                                              short* __restrict__ xeT) {
  __shared__ float tile[64][129];
  __shared__ int toks[64];
  __shared__ float msk[64];
  int bid = blockIdx.x;
  int xcd = bid & 7, slot = bid >> 3;
  int b = xcd + 8 * (slot / 13);
  int mt = slot % 13;
  int m0 = mt * 64;
  int t = threadIdx.x;
  if (t < 64) {
    int gm = m0 + t;
    toks[t] = (gm < LL) ? x[b * LL + gm] : 1;
    msk[t] = (gm < LL) ? (float)mask[b * LL + gm] : 0.f;
  }
  __syncthreads();
  for (int i = t; i < 64 * 128; i += 256) {
    int m = i >> 7, d = i & 127;
    int gm = m0 + m;
    float v = 0.f;
    if (gm < LL && d < DD) v = emb[(size_t)toks[m] * DD + d];
    tile[m][d] = v;
    xeb[((size_t)b * MPAD + gm) * DPAD + d] = (short)f2bf(v);
  }
  __syncthreads();
  for (int i = t; i < 64 * 128; i += 256) {
    int m = i & 63, d = i >> 6;
    float mk = msk[m];
    float v;
    if (d < DD) v = tile[m][d] * mk;
    else if (d == DD) v = mk;
    else if (d == DD + 1) v = (m0 + m < LL) ? 1.f : 0.f;
    else v = 0.f;
    xeT[((size_t)b * DPAD + d) * MPAD + m0 + m] = (short)f2bf(v);
  }
}

// ---- bf16 weight pack: wb[br][sz][nf(64)][i(5)][d(128)] zero-padded ----
__global__ __launch_bounds__(256) void k_wprep(ConvP P, short* __restrict__ wb) {
  int idx = blockIdx.x * 256 + threadIdx.x;
  if (idx >= 2 * 4 * 64 * 5 * 128) return;
  int d = idx & 127;
  int r = idx >> 7;
  int i = r % 5; r /= 5;
  int nf = r & 63; r >>= 6;
  int sz = r & 3;
  int br = r >> 2;
  int s = (sz < 3) ? sz + 1 : 5;
  float v = 0.f;
  if (nf < NFC && i < s && d < DD) v = P.w[br * 4 + sz][(nf * s + i) * DD + d];
  wb[idx] = (short)f2bf(v);
}

// ---- MFMA attention: 2-phase LDS pipeline (reg-staged dbuf), permlane softmax ----
#define ASTR 136
#define BOFF (32 * ASTR)
#define SBSZ (BOFF + 112 * 32)
__global__ __launch_bounds__(256, 3) void k_attn(const short* __restrict__ xeb,
                                                 const short* __restrict__ xeT,
                                                 const int* __restrict__ mask,
                                                 short* __restrict__ xhb) {
  __shared__ __align__(16) short SB[2][SBSZ];
  int bid = blockIdx.x;
  int xcd = bid & 7, slot = bid >> 3;  // batch -> XCD: panels stay L2-local
  int b = xcd + 8 * (slot / 13);
  int lt = slot % 13;
  int l0 = lt * 64;
  int t = threadIdx.x, w = t >> 6, lane = t & 63, g = lane >> 4, c = lane & 15;
  int lcol = l0 + 16 * w + c;

  const short* xebB = xeb + (size_t)b * MPAD * DPAD;
  const short* xTb = xeT + (size_t)b * DPAD * MPAD;

  // per-lane staging assignment: q = p*256 + w*64 + lane
  const short* ssrc[4];
  int sdst[4], sstep[4];
  bool sval[4];
#pragma unroll
  for (int p = 0; p < 4; ++p) {
    int q = p * 256 + w * 64 + lane;
    if (q < 512) {  // As chunk: row r of 32-m tile, 16B piece j
      int r = q >> 4, j = q & 15;
      ssrc[p] = xebB + r * DPAD + j * 8;
      sstep[p] = 32 * DPAD;
      sdst[p] = r * ASTR + j * 8;
      sval[p] = true;
    } else {  // Bs chunk: row r (d-dim), 16B piece j of the 32-m slice
      int u = q - 512;
      int r = u >> 2, j = u & 3;
      ssrc[p] = xTb + r * MPAD + j * 8;
      sstep[p] = 32;
      sdst[p] = BOFF + r * 32 + j * 8;
      sval[p] = (u < 448);
    }
  }

  short8 xlf[4];
  {
    const short* xrow = xebB + (size_t)lcol * DPAD + 8 * g;
#pragma unroll
    for (int ks = 0; ks < 4; ++ks)
      xlf[ks] = *reinterpret_cast<const short8*>(xrow + 32 * ks);
  }

  f32x4 pv[7];
#pragma unroll
  for (int dt = 0; dt < 7; ++dt) pv[dt] = (f32x4){0.f, 0.f, 0.f, 0.f};

  uint4 R[4];
#pragma unroll
  for (int p = 0; p < 4; ++p) {
    if (sval[p]) R[p] = *reinterpret_cast<const uint4*>(ssrc[p]);
    ssrc[p] += sstep[p];
  }

  int cur = 0;
  for (int mc = 0; mc < 26; ++mc) {
    int m0 = mc * 32;
#pragma unroll
    for (int p = 0; p < 4; ++p)
      if (sval[p]) *reinterpret_cast<short8*>(&SB[cur][sdst[p]]) =
          *reinterpret_cast<const short8*>(&R[p]);
    if (mc < 25) {
#pragma unroll
      for (int p = 0; p < 4; ++p) {
        if (sval[p]) R[p] = *reinterpret_cast<const uint4*>(ssrc[p]);
        ssrc[p] += sstep[p];
      }
    }
    asm volatile("s_waitcnt lgkmcnt(0)" ::: "memory");
    __builtin_amdgcn_s_barrier();
    __builtin_amdgcn_sched_barrier(0);

    const short* asb = SB[cur];
    const short* bsb = SB[cur] + BOFF;

    f32x4 s0 = {0.f, 0.f, 0.f, 0.f}, s1 = {0.f, 0.f, 0.f, 0.f};
#pragma unroll
    for (int ks = 0; ks < 4; ++ks) {
      short8 af0 = *reinterpret_cast<const short8*>(asb + c * ASTR + 8 * g + 32 * ks);
      short8 af1 = *reinterpret_cast<const short8*>(asb + (c + 16) * ASTR + 8 * g + 32 * ks);
      s0 = MFMA16(af0, xlf[ks], s0);
      s1 = MFMA16(af1, xlf[ks], s1);
    }

    float e00 = __expf(s0[0]), e01 = __expf(s0[1]), e02 = __expf(s0[2]), e03 = __expf(s0[3]);
    float e10 = __expf(s1[0]), e11 = __expf(s1[1]), e12 = __expf(s1[2]), e13 = __expf(s1[3]);
    if ((mc >> 1) == lt) {
      int md = m0 + 4 * g;
      e00 = (md + 0 == lcol) ? 0.f : e00;
      e01 = (md + 1 == lcol) ? 0.f : e01;
      e02 = (md + 2 == lcol) ? 0.f : e02;
      e03 = (md + 3 == lcol) ? 0.f : e03;
      e10 = (md + 16 == lcol) ? 0.f : e10;
      e11 = (md + 17 == lcol) ? 0.f : e11;
      e12 = (md + 18 == lcol) ? 0.f : e12;
      e13 = (md + 19 == lcol) ? 0.f : e13;
    }
    unsigned x0 = cvtpk(e00, e01), x1 = cvtpk(e02, e03);
    unsigned x2 = cvtpk(e10, e11), x3 = cvtpk(e12, e13);
    swap3216(x0, x2);
    swap3216(x1, x3);
    union { unsigned u[4]; short8 v; } pa;
    pa.u[0] = x0; pa.u[1] = x1; pa.u[2] = x2; pa.u[3] = x3;

#pragma unroll
    for (int dt = 0; dt < 7; ++dt) {
      short8 bf = *reinterpret_cast<const short8*>(bsb + (c + 16 * dt) * 32 + 8 * g);
      pv[dt] = MFMA16(pa.v, bf, pv[dt]);
    }
    cur ^= 1;
  }

#pragma unroll
  for (int r = 0; r < 4; ++r) {
    int lrow = l0 + 16 * w + 4 * g + r;
    float S2r = __shfl(pv[6][r], 16 * g + 4);
    float Zr = __shfl(pv[6][r], 16 * g + 5) + 1.0f;  // +1: diag exp(0)
    short* xhr = xhb + ((size_t)b * MPAD + lrow) * DPAD;
    if (lrow < LL) {
      float mlr = (float)mask[b * LL + lrow];
      float inv = mlr / (mlr * S2r + Zr * 1e-13f);
      const short* xer = xebB + (size_t)lrow * DPAD;
#pragma unroll
      for (int dt = 0; dt < 7; ++dt) {
        int d = 16 * dt + c;
        xhr[d] = (d < DD) ? (short)f2bf(pv[dt][r] * inv + bf2f(xer[d])) : (short)0;
      }
      xhr[112 + c] = 0;
    } else {
#pragma unroll
      for (int dt = 0; dt < 8; ++dt) xhr[16 * dt + c] = 0;
    }
  }
}

// ---- conv: LDS-free. wave = 16-row l-slice (lsub=w); A-frags in regs, weights
// streamed from L1/L2 (identical across waves -> broadcast). No staging barrier.
__global__ __launch_bounds__(256) void k_conv(const short* __restrict__ xeb,
                                              const short* __restrict__ xhb,
                                              const short* __restrict__ wb,
                                              ConvP P, int* __restrict__ feat) {
  __shared__ float smx[4][4][4][16];  // [wave][sz][nfg][c]
  int bid = blockIdx.x;
  int xcd = bid & 7, slot = bid >> 3;  // batch -> XCD map (L2-local x panels)
  int b = xcd + 8 * (slot / 26);
  int rem = slot % 26;
  int br = rem >= 13;
  int ltile = rem % 13;
  int l0 = ltile * 64;
  const short* src = (br ? xhb : xeb) + (size_t)b * MPAD * DPAD;
  int t = threadIdx.x, w = t >> 6, lane = t & 63, g = lane >> 4, c = lane & 15;

  // A-fragments in registers: rows l0 + 16w + c + i2 (zero rows past 800 via clamp)
  short8 af[5][4];
#pragma unroll
  for (int i2 = 0; i2 < 5; ++i2) {
    int gr = l0 + 16 * w + c + i2;
    if (gr > MPAD - 1) gr = MPAD - 1;  // rows 800..831 are zeros
    const short* rp = src + (size_t)gr * DPAD + 8 * g;
#pragma unroll
    for (int ks = 0; ks < 4; ++ks)
      af[i2][ks] = *reinterpret_cast<const short8*>(rp + 32 * ks);
  }

  const short* wbase = wb + (size_t)(br * 4) * 64 * 640 + (size_t)c * 640 + 8 * g;

#pragma unroll
  for (int nfg = 0; nfg < 4; ++nfg) {
#pragma unroll
    for (int sz = 0; sz < 4; ++sz) {
      const int S = (sz == 3) ? 5 : sz + 1;
      const short* wp = wbase + ((size_t)sz * 64 + nfg * 16) * 640;
      f32x4 acc = (f32x4){0.f, 0.f, 0.f, 0.f};
#pragma unroll
      for (int i2 = 0; i2 < S; ++i2)
#pragma unroll
        for (int ks = 0; ks < 4; ++ks) {
          short8 wfl = *reinterpret_cast<const short8*>(wp + i2 * 128 + ks * 32);
          acc = MFMA16(af[i2][ks], wfl, acc);
        }
      int nf = nfg * 16 + c;
      float bias = (nf < NFC) ? P.bias[br * 4 + sz][nf] : 0.f;
      const int Lout = LL - S + 1;
      float m = 0.f;
#pragma unroll
      for (int r = 0; r < 4; ++r) {
        int l = l0 + 16 * w + 4 * g + r;
        float v = acc[r] + bias;
        v = v > 0.f ? v : 0.f;
        if (l < Lout) m = fmaxf(m, v);
      }
      m = fmaxf(m, __shfl_xor(m, 16));
      m = fmaxf(m, __shfl_xor(m, 32));
      if (g == 0) smx[w][sz][nfg][c] = m;
    }
  }
  __syncthreads();
  // cross-wave reduce + one atomic pass: t -> (sz,nfg,c)
  {
    int c2 = t & 15, nfg2 = (t >> 4) & 3, sz2 = t >> 6;
    float m = fmaxf(fmaxf(smx[0][sz2][nfg2][c2], smx[1][sz2][nfg2][c2]),
                    fmaxf(smx[2][sz2][nfg2][c2], smx[3][sz2][nfg2][c2]));
    int nf = nfg2 * 16 + c2;
    if (nf < NFC)
      atomicMax(&feat[((b * 2 + br) * 4 + sz2) * NFC + nf], __float_as_int(m));
  }
}

// ---------------- FC + branch sum ----------------
__global__ __launch_bounds__(256) void k_fc(const float* __restrict__ feat,
                                            const float* __restrict__ fw1,
                                            const float* __restrict__ fb1,
                                            const float* __restrict__ fw2,
                                            const float* __restrict__ fb2,
                                            float* __restrict__ out) {
  int id = blockIdx.x * 256 + threadIdx.x;
  if (id >= BB * NFC) return;
  int b = id / NFC, k = id - b * NFC;
  float a = fb1[k] + fb2[k];
  const float* f1 = feat + (size_t)(b * 2 + 0) * (4 * NFC);
  const float* f2 = feat + (size_t)(b * 2 + 1) * (4 * NFC);
  const float* w1 = fw1 + k * (4 * NFC);
  const float* w2 = fw2 + k * (4 * NFC);
  for (int j = 0; j < 4 * NFC; ++j) a += f1[j] * w1[j] + f2[j] * w2[j];
  out[id] = a;
}

extern "C" void kernel_launch(void* const* d_in, const int* in_sizes, int n_in,
                              void* d_out, int out_size, void* d_ws, size_t ws_size,
                              hipStream_t stream) {
  const int* x = (const int*)d_in[0];
  const int* mask = (const int*)d_in[2];
  const float* emb = (const float*)d_in[3];
  ConvP P;
  for (int br = 0; br < 2; ++br)
    for (int j = 0; j < 4; ++j) {
      P.w[br * 4 + j] = (const float*)d_in[4 + br * 10 + j * 2];
      P.bias[br * 4 + j] = (const float*)d_in[4 + br * 10 + j * 2 + 1];
    }
  const float* fw1 = (const float*)d_in[12];
  const float* fb1 = (const float*)d_in[13];
  const float* fw2 = (const float*)d_in[22];
  const float* fb2 = (const float*)d_in[23];

  char* base = (char*)d_ws;
  short* xeb = (short*)base;                    // 13,631,488 B
  short* xeT = (short*)(base + 13631488);       // 13,631,488 B
  short* xhb = (short*)(base + 27262976);       // 13,631,488 B
  short* wb = (short*)(base + 40894464);        //    655,360 B
  int* feat = (int*)(base + 41549824);          //    102,400 B
  float* out = (float*)d_out;

  hipMemsetAsync(feat, 0, (size_t)BB * 2 * 4 * NFC * sizeof(int), stream);
  k_prep<<<BB * 13, 256, 0, stream>>>(x, emb, mask, xeb, xeT);
  k_wprep<<<(2 * 4 * 64 * 5 * 128 + 255) / 256, 256, 0, stream>>>(P, wb);
  k_attn<<<BB * 13, 256, 0, stream>>>(xeb, xeT, mask, xhb);
  k_conv<<<BB * 2 * 13, 256, 0, stream>>>(xeb, xhb, wb, P, feat);
  k_fc<<<(BB * NFC + 255) / 256, 256, 0, stream>>>((const float*)feat, fw1, fb1,
                                                   fw2, fb2, out);
}

// Round 9
// 137.388 us; speedup vs baseline: 1.7571x; 1.7571x over previous
//
#include <hip/hip_runtime.h>
#include <hip/hip_bf16.h>

#define BB 64
#define LL 800
#define DD 100
#define NFC 50
#define MPAD 832
#define DPAD 128

typedef __attribute__((ext_vector_type(8))) short short8;
typedef __attribute__((ext_vector_type(4))) float f32x4;
#define MFMA16(a, b, c) __builtin_amdgcn_mfma_f32_16x16x32_bf16(a, b, c, 0, 0, 0)

struct ConvP {
  const float* w[8];
  const float* bias[8];
};

__device__ __forceinline__ ushort f2bf(float f) {
  unsigned u = __float_as_uint(f);
  u += 0x7fff + ((u >> 16) & 1);
  return (ushort)(u >> 16);
}
__device__ __forceinline__ float bf2f(short s) {
  return __uint_as_float(((unsigned)(ushort)s) << 16);
}
__device__ __forceinline__ unsigned cvtpk(float lo, float hi) {
  unsigned d;
  asm("v_cvt_pk_bf16_f32 %0, %1, %2" : "=v"(d) : "v"(lo), "v"(hi));
  return d;
}
__device__ __forceinline__ void swap3216(unsigned& a, unsigned& b) {
  asm("v_permlane32_swap_b32 %0, %1\n\t"
      "v_permlane16_swap_b32 %0, %1"
      : "+v"(a), "+v"(b));
}

// ---- fused gather + bf16 prep ----
// xeb[b][832][128]  : raw bf16 rows
// xeT[b][128][832]  : transposed, MASKED (d<100: x*mask; d=100: mask; d=101: 1; else 0)
__global__ __launch_bounds__(256) void k_prep(const int* __restrict__ x,
                                              const float* __restrict__ emb,
                                              const int* __restrict__ mask,
                                              short* __restrict__ xeb,
                                              short* __restrict__ xeT) {
  __shared__ float tile[64][129];
  __shared__ int toks[64];
  __shared__ float msk[64];
  int bid = blockIdx.x;
  int xcd = bid & 7, slot = bid >> 3;
  int b = xcd + 8 * (slot / 13);
  int mt = slot % 13;
  int m0 = mt * 64;
  int t = threadIdx.x;
  if (t < 64) {
    int gm = m0 + t;
    toks[t] = (gm < LL) ? x[b * LL + gm] : 1;
    msk[t] = (gm < LL) ? (float)mask[b * LL + gm] : 0.f;
  }
  __syncthreads();
  for (int i = t; i < 64 * 128; i += 256) {
    int m = i >> 7, d = i & 127;
    int gm = m0 + m;
    float v = 0.f;
    if (gm < LL && d < DD) v = emb[(size_t)toks[m] * DD + d];
    tile[m][d] = v;
    xeb[((size_t)b * MPAD + gm) * DPAD + d] = (short)f2bf(v);
  }
  __syncthreads();
  for (int i = t; i < 64 * 128; i += 256) {
    int m = i & 63, d = i >> 6;
    float mk = msk[m];
    float v;
    if (d < DD) v = tile[m][d] * mk;
    else if (d == DD) v = mk;
    else if (d == DD + 1) v = (m0 + m < LL) ? 1.f : 0.f;
    else v = 0.f;
    xeT[((size_t)b * DPAD + d) * MPAD + m0 + m] = (short)f2bf(v);
  }
}

// ---- bf16 weight pack: wb[br][sz][nf(64)][i(5)][d(128)] zero-padded ----
__global__ __launch_bounds__(256) void k_wprep(ConvP P, short* __restrict__ wb) {
  int idx = blockIdx.x * 256 + threadIdx.x;
  if (idx >= 2 * 4 * 64 * 5 * 128) return;
  int d = idx & 127;
  int r = idx >> 7;
  int i = r % 5; r /= 5;
  int nf = r & 63; r >>= 6;
  int sz = r & 3;
  int br = r >> 2;
  int s = (sz < 3) ? sz + 1 : 5;
  float v = 0.f;
  if (nf < NFC && i < s && d < DD) v = P.w[br * 4 + sz][(nf * s + i) * DD + d];
  wb[idx] = (short)f2bf(v);
}

// ---- MFMA attention: 2-phase LDS pipeline (reg-staged dbuf), permlane softmax ----
#define ASTR 136
#define BOFF (32 * ASTR)
#define SBSZ (BOFF + 112 * 32)
__global__ __launch_bounds__(256, 3) void k_attn(const short* __restrict__ xeb,
                                                 const short* __restrict__ xeT,
                                                 const int* __restrict__ mask,
                                                 short* __restrict__ xhb) {
  __shared__ __align__(16) short SB[2][SBSZ];
  int bid = blockIdx.x;
  int xcd = bid & 7, slot = bid >> 3;  // batch -> XCD: panels stay L2-local
  int b = xcd + 8 * (slot / 13);
  int lt = slot % 13;
  int l0 = lt * 64;
  int t = threadIdx.x, w = t >> 6, lane = t & 63, g = lane >> 4, c = lane & 15;
  int lcol = l0 + 16 * w + c;

  const short* xebB = xeb + (size_t)b * MPAD * DPAD;
  const short* xTb = xeT + (size_t)b * DPAD * MPAD;

  // per-lane staging assignment: q = p*256 + w*64 + lane
  const short* ssrc[4];
  int sdst[4], sstep[4];
  bool sval[4];
#pragma unroll
  for (int p = 0; p < 4; ++p) {
    int q = p * 256 + w * 64 + lane;
    if (q < 512) {  // As chunk: row r of 32-m tile, 16B piece j
      int r = q >> 4, j = q & 15;
      ssrc[p] = xebB + r * DPAD + j * 8;
      sstep[p] = 32 * DPAD;
      sdst[p] = r * ASTR + j * 8;
      sval[p] = true;
    } else {  // Bs chunk: row r (d-dim), 16B piece j of the 32-m slice
      int u = q - 512;
      int r = u >> 2, j = u & 3;
      ssrc[p] = xTb + r * MPAD + j * 8;
      sstep[p] = 32;
      sdst[p] = BOFF + r * 32 + j * 8;
      sval[p] = (u < 448);
    }
  }

  short8 xlf[4];
  {
    const short* xrow = xebB + (size_t)lcol * DPAD + 8 * g;
#pragma unroll
    for (int ks = 0; ks < 4; ++ks)
      xlf[ks] = *reinterpret_cast<const short8*>(xrow + 32 * ks);
  }

  f32x4 pv[7];
#pragma unroll
  for (int dt = 0; dt < 7; ++dt) pv[dt] = (f32x4){0.f, 0.f, 0.f, 0.f};

  uint4 R[4];
#pragma unroll
  for (int p = 0; p < 4; ++p) {
    if (sval[p]) R[p] = *reinterpret_cast<const uint4*>(ssrc[p]);
    ssrc[p] += sstep[p];
  }

  int cur = 0;
  for (int mc = 0; mc < 26; ++mc) {
    int m0 = mc * 32;
#pragma unroll
    for (int p = 0; p < 4; ++p)
      if (sval[p]) *reinterpret_cast<short8*>(&SB[cur][sdst[p]]) =
          *reinterpret_cast<const short8*>(&R[p]);
    if (mc < 25) {
#pragma unroll
      for (int p = 0; p < 4; ++p) {
        if (sval[p]) R[p] = *reinterpret_cast<const uint4*>(ssrc[p]);
        ssrc[p] += sstep[p];
      }
    }
    asm volatile("s_waitcnt lgkmcnt(0)" ::: "memory");
    __builtin_amdgcn_s_barrier();
    __builtin_amdgcn_sched_barrier(0);

    const short* asb = SB[cur];
    const short* bsb = SB[cur] + BOFF;

    f32x4 s0 = {0.f, 0.f, 0.f, 0.f}, s1 = {0.f, 0.f, 0.f, 0.f};
    __builtin_amdgcn_s_setprio(1);
#pragma unroll
    for (int ks = 0; ks < 4; ++ks) {
      short8 af0 = *reinterpret_cast<const short8*>(asb + c * ASTR + 8 * g + 32 * ks);
      short8 af1 = *reinterpret_cast<const short8*>(asb + (c + 16) * ASTR + 8 * g + 32 * ks);
      s0 = MFMA16(af0, xlf[ks], s0);
      s1 = MFMA16(af1, xlf[ks], s1);
    }
    __builtin_amdgcn_s_setprio(0);

    float e00 = __expf(s0[0]), e01 = __expf(s0[1]), e02 = __expf(s0[2]), e03 = __expf(s0[3]);
    float e10 = __expf(s1[0]), e11 = __expf(s1[1]), e12 = __expf(s1[2]), e13 = __expf(s1[3]);
    if ((mc >> 1) == lt) {
      int md = m0 + 4 * g;
      e00 = (md + 0 == lcol) ? 0.f : e00;
      e01 = (md + 1 == lcol) ? 0.f : e01;
      e02 = (md + 2 == lcol) ? 0.f : e02;
      e03 = (md + 3 == lcol) ? 0.f : e03;
      e10 = (md + 16 == lcol) ? 0.f : e10;
      e11 = (md + 17 == lcol) ? 0.f : e11;
      e12 = (md + 18 == lcol) ? 0.f : e12;
      e13 = (md + 19 == lcol) ? 0.f : e13;
    }
    unsigned x0 = cvtpk(e00, e01), x1 = cvtpk(e02, e03);
    unsigned x2 = cvtpk(e10, e11), x3 = cvtpk(e12, e13);
    swap3216(x0, x2);
    swap3216(x1, x3);
    union { unsigned u[4]; short8 v; } pa;
    pa.u[0] = x0; pa.u[1] = x1; pa.u[2] = x2; pa.u[3] = x3;

    __builtin_amdgcn_s_setprio(1);
#pragma unroll
    for (int dt = 0; dt < 7; ++dt) {
      short8 bf = *reinterpret_cast<const short8*>(bsb + (c + 16 * dt) * 32 + 8 * g);
      pv[dt] = MFMA16(pa.v, bf, pv[dt]);
    }
    __builtin_amdgcn_s_setprio(0);
    cur ^= 1;
  }

#pragma unroll
  for (int r = 0; r < 4; ++r) {
    int lrow = l0 + 16 * w + 4 * g + r;
    float S2r = __shfl(pv[6][r], 16 * g + 4);
    float Zr = __shfl(pv[6][r], 16 * g + 5) + 1.0f;  // +1: diag exp(0)
    short* xhr = xhb + ((size_t)b * MPAD + lrow) * DPAD;
    if (lrow < LL) {
      float mlr = (float)mask[b * LL + lrow];
      float inv = mlr / (mlr * S2r + Zr * 1e-13f);
      const short* xer = xebB + (size_t)lrow * DPAD;
#pragma unroll
      for (int dt = 0; dt < 7; ++dt) {
        int d = 16 * dt + c;
        xhr[d] = (d < DD) ? (short)f2bf(pv[dt][r] * inv + bf2f(xer[d])) : (short)0;
      }
      xhr[112 + c] = 0;
    } else {
#pragma unroll
      for (int dt = 0; dt < 8; ++dt) xhr[16 * dt + c] = 0;
    }
  }
}

// ---- conv v2: i2-major, ALL 44 weight frags preloaded once (reused 4 lsubs),
// A-frags streamed from LDS in 4-read batches -> 80 LDS reads/wave (was 176).
__global__ __launch_bounds__(256, 2) void k_conv(const short* __restrict__ xeb,
                                                 const short* __restrict__ xhb,
                                                 const short* __restrict__ wb,
                                                 ConvP P, int* __restrict__ feat) {
  __shared__ __align__(16) short xt[68 * 128];
  int bid = blockIdx.x;
  int xcd = bid & 7, slot = bid >> 3;  // batch -> XCD map (L2-local x panels)
  int b = xcd + 8 * (slot / 26);
  int rem = slot % 26;
  int br = rem >= 13;
  int ltile = rem % 13;
  int l0 = ltile * 64;
  const short* src = (br ? xhb : xeb) + (size_t)b * MPAD * DPAD;
  int t = threadIdx.x;
  int w = t >> 6, lane = t & 63, g = lane >> 4, c = lane & 15;
  int nf = w * 16 + c;
  const short* wpb = wb + (size_t)(br * 4) * 64 * 640 + (size_t)nf * 640 + 8 * g;

  // preload ALL weight fragments (issued before the staging barrier; L2-hot)
  short8 wf1[1][4], wf2[2][4], wf3[3][4], wf5[5][4];
#pragma unroll
  for (int ks = 0; ks < 4; ++ks)
    wf1[0][ks] = *reinterpret_cast<const short8*>(wpb + (size_t)0 * 40960 + 0 * 128 + ks * 32);
#pragma unroll
  for (int i2 = 0; i2 < 2; ++i2)
#pragma unroll
    for (int ks = 0; ks < 4; ++ks)
      wf2[i2][ks] = *reinterpret_cast<const short8*>(wpb + (size_t)1 * 40960 + i2 * 128 + ks * 32);
#pragma unroll
  for (int i2 = 0; i2 < 3; ++i2)
#pragma unroll
    for (int ks = 0; ks < 4; ++ks)
      wf3[i2][ks] = *reinterpret_cast<const short8*>(wpb + (size_t)2 * 40960 + i2 * 128 + ks * 32);
#pragma unroll
  for (int i2 = 0; i2 < 5; ++i2)
#pragma unroll
    for (int ks = 0; ks < 4; ++ks)
      wf5[i2][ks] = *reinterpret_cast<const short8*>(wpb + (size_t)3 * 40960 + i2 * 128 + ks * 32);

  float bias0 = (nf < NFC) ? P.bias[br * 4 + 0][nf] : 0.f;
  float bias1 = (nf < NFC) ? P.bias[br * 4 + 1][nf] : 0.f;
  float bias2 = (nf < NFC) ? P.bias[br * 4 + 2][nf] : 0.f;
  float bias3 = (nf < NFC) ? P.bias[br * 4 + 3][nf] : 0.f;

  // stage 68 rows x 128 cols bf16, XOR-swizzled 16B chunks (chunk ^= row&7)
  for (int i = t; i < 68 * 16; i += 256) {
    int row = i >> 4, c16 = i & 15;
    int gr = l0 + row;
    if (gr > MPAD - 1) gr = MPAD - 1;  // rows >=800 are zero
    short8 v = *reinterpret_cast<const short8*>(src + (size_t)gr * DPAD + c16 * 8);
    *reinterpret_cast<short8*>(&xt[row * 128 + ((c16 ^ (row & 7)) << 3)]) = v;
  }
  __syncthreads();

  float mx0 = 0.f, mx1 = 0.f, mx2 = 0.f, mx3 = 0.f;
#pragma unroll
  for (int lsub = 0; lsub < 4; ++lsub) {
    f32x4 a0 = (f32x4){0.f, 0.f, 0.f, 0.f};
    f32x4 a1 = a0, a2 = a0, a3 = a0;
#pragma unroll
    for (int i2 = 0; i2 < 5; ++i2) {
      int row = lsub * 16 + c + i2;
      int rb = row * 128, rx = row & 7;
      short8 af0 = *reinterpret_cast<const short8*>(&xt[rb + (((0 + g) ^ rx) << 3)]);
      short8 af1 = *reinterpret_cast<const short8*>(&xt[rb + (((4 + g) ^ rx) << 3)]);
      short8 af2 = *reinterpret_cast<const short8*>(&xt[rb + (((8 + g) ^ rx) << 3)]);
      short8 af3 = *reinterpret_cast<const short8*>(&xt[rb + (((12 + g) ^ rx) << 3)]);
      if (i2 < 1) {
        a0 = MFMA16(af0, wf1[0][0], a0);
        a0 = MFMA16(af1, wf1[0][1], a0);
        a0 = MFMA16(af2, wf1[0][2], a0);
        a0 = MFMA16(af3, wf1[0][3], a0);
      }
      if (i2 < 2) {
        a1 = MFMA16(af0, wf2[i2 < 2 ? i2 : 0][0], a1);
        a1 = MFMA16(af1, wf2[i2 < 2 ? i2 : 0][1], a1);
        a1 = MFMA16(af2, wf2[i2 < 2 ? i2 : 0][2], a1);
        a1 = MFMA16(af3, wf2[i2 < 2 ? i2 : 0][3], a1);
      }
      if (i2 < 3) {
        a2 = MFMA16(af0, wf3[i2 < 3 ? i2 : 0][0], a2);
        a2 = MFMA16(af1, wf3[i2 < 3 ? i2 : 0][1], a2);
        a2 = MFMA16(af2, wf3[i2 < 3 ? i2 : 0][2], a2);
        a2 = MFMA16(af3, wf3[i2 < 3 ? i2 : 0][3], a2);
      }
      a3 = MFMA16(af0, wf5[i2][0], a3);
      a3 = MFMA16(af1, wf5[i2][1], a3);
      a3 = MFMA16(af2, wf5[i2][2], a3);
      a3 = MFMA16(af3, wf5[i2][3], a3);
    }
    // per-lsub epilogue: bias + relu + Lout mask -> running max
#pragma unroll
    for (int r = 0; r < 4; ++r) {
      int l = l0 + lsub * 16 + 4 * g + r;
      float v0 = a0[r] + bias0; v0 = v0 > 0.f ? v0 : 0.f;
      float v1 = a1[r] + bias1; v1 = v1 > 0.f ? v1 : 0.f;
      float v2 = a2[r] + bias2; v2 = v2 > 0.f ? v2 : 0.f;
      float v3 = a3[r] + bias3; v3 = v3 > 0.f ? v3 : 0.f;
      if (l < LL - 0) mx0 = fmaxf(mx0, v0);
      if (l < LL - 1) mx1 = fmaxf(mx1, v1);
      if (l < LL - 2) mx2 = fmaxf(mx2, v2);
      if (l < LL - 4) mx3 = fmaxf(mx3, v3);
    }
  }

  mx0 = fmaxf(mx0, __shfl_xor(mx0, 16));
  mx0 = fmaxf(mx0, __shfl_xor(mx0, 32));
  mx1 = fmaxf(mx1, __shfl_xor(mx1, 16));
  mx1 = fmaxf(mx1, __shfl_xor(mx1, 32));
  mx2 = fmaxf(mx2, __shfl_xor(mx2, 16));
  mx2 = fmaxf(mx2, __shfl_xor(mx2, 32));
  mx3 = fmaxf(mx3, __shfl_xor(mx3, 16));
  mx3 = fmaxf(mx3, __shfl_xor(mx3, 32));
  if (g == 0 && nf < NFC) {
    int base = (b * 2 + br) * 4;
    atomicMax(&feat[(base + 0) * NFC + nf], __float_as_int(mx0));
    atomicMax(&feat[(base + 1) * NFC + nf], __float_as_int(mx1));
    atomicMax(&feat[(base + 2) * NFC + nf], __float_as_int(mx2));
    atomicMax(&feat[(base + 3) * NFC + nf], __float_as_int(mx3));
  }
}

// ---------------- FC + branch sum ----------------
__global__ __launch_bounds__(256) void k_fc(const float* __restrict__ feat,
                                            const float* __restrict__ fw1,
                                            const float* __restrict__ fb1,
                                            const float* __restrict__ fw2,
                                            const float* __restrict__ fb2,
                                            float* __restrict__ out) {
  int id = blockIdx.x * 256 + threadIdx.x;
  if (id >= BB * NFC) return;
  int b = id / NFC, k = id - b * NFC;
  float a = fb1[k] + fb2[k];
  const float* f1 = feat + (size_t)(b * 2 + 0) * (4 * NFC);
  const float* f2 = feat + (size_t)(b * 2 + 1) * (4 * NFC);
  const float* w1 = fw1 + k * (4 * NFC);
  const float* w2 = fw2 + k * (4 * NFC);
  for (int j = 0; j < 4 * NFC; ++j) a += f1[j] * w1[j] + f2[j] * w2[j];
  out[id] = a;
}

extern "C" void kernel_launch(void* const* d_in, const int* in_sizes, int n_in,
                              void* d_out, int out_size, void* d_ws, size_t ws_size,
                              hipStream_t stream) {
  const int* x = (const int*)d_in[0];
  const int* mask = (const int*)d_in[2];
  const float* emb = (const float*)d_in[3];
  ConvP P;
  for (int br = 0; br < 2; ++br)
    for (int j = 0; j < 4; ++j) {
      P.w[br * 4 + j] = (const float*)d_in[4 + br * 10 + j * 2];
      P.bias[br * 4 + j] = (const float*)d_in[4 + br * 10 + j * 2 + 1];
    }
  const float* fw1 = (const float*)d_in[12];
  const float* fb1 = (const float*)d_in[13];
  const float* fw2 = (const float*)d_in[22];
  const float* fb2 = (const float*)d_in[23];

  char* base = (char*)d_ws;
  short* xeb = (short*)base;                    // 13,631,488 B
  short* xeT = (short*)(base + 13631488);       // 13,631,488 B
  short* xhb = (short*)(base + 27262976);       // 13,631,488 B
  short* wb = (short*)(base + 40894464);        //    655,360 B
  int* feat = (int*)(base + 41549824);          //    102,400 B
  float* out = (float*)d_out;

  hipMemsetAsync(feat, 0, (size_t)BB * 2 * 4 * NFC * sizeof(int), stream);
  k_prep<<<BB * 13, 256, 0, stream>>>(x, emb, mask, xeb, xeT);
  k_wprep<<<(2 * 4 * 64 * 5 * 128 + 255) / 256, 256, 0, stream>>>(P, wb);
  k_attn<<<BB * 13, 256, 0, stream>>>(xeb, xeT, mask, xhb);
  k_conv<<<BB * 2 * 13, 256, 0, stream>>>(xeb, xhb, wb, P, feat);
  k_fc<<<(BB * NFC + 255) / 256, 256, 0, stream>>>((const float*)feat, fw1, fb1,
                                                   fw2, fb2, out);
}